// Round 2
// baseline (629.197 us; speedup 1.0000x reference)
//
#include <hip/hip_runtime.h>
#include <stdint.h>

using f4v = __attribute__((ext_vector_type(4))) float;
using s8v = __attribute__((ext_vector_type(8))) short;

constexpr int C_ = 128, H_ = 128, W_ = 128, HW_ = H_ * W_;
constexpr int S_ = 4;             // y-splits for k_dw
constexpr int OROWS = H_ / S_;    // 32 output rows per block
static_assert(OROWS == 32, "bias table indexing assumes 32 rows/block");

__device__ __forceinline__ unsigned f2bf(float f) {
  union { float f; unsigned u; } v; v.f = f;
  return (v.u + 0x7FFFu + ((v.u >> 16) & 1u)) >> 16;   // RTNE
}

// ---------------------------------------------------------------------------
// Kernel 1: fused depthwise branches -> add (bf16), column-sweep with circular
// register accumulators. Block = 8 channels x 32-col strip x 32 output rows.
// Round-2 changes:
//  * XCD-chunked swizzle: all 16 blocks of one (n,g) tile (4 xstrips x 4 ybs,
//    which share halo cache lines) land on one XCD -> halo refetch becomes L2
//    hit instead of HBM miss (fetch was 3x amplified).
//  * Async-stage split (T14): next chunk's 6 float4 loads issued into regs
//    BEFORE the 16-row compute; regs->LDS commit after the barrier. Load
//    latency hides under compute instead of draining at the barrier.
// ws layout: [n][g=c/8][p=h*128+w][c%8] bf16 (16B per pixel-group).
// ---------------------------------------------------------------------------
__global__ __launch_bounds__(256, 4) void k_dw(
    const float* __restrict__ x,
    const float* __restrict__ w0,  const float* __restrict__ b0,
    const float* __restrict__ w01, const float* __restrict__ b01,
    const float* __restrict__ w02, const float* __restrict__ b02,
    const float* __restrict__ w11, const float* __restrict__ b11,
    const float* __restrict__ w12, const float* __restrict__ b12,
    unsigned short* __restrict__ ws)
{
  __shared__ float xs[8][16][48];            // 16-row chunk + 8-col halo each side
  __shared__ unsigned short ebuf[16][8][32]; // emit transpose buffer [row][ch][x]
  __shared__ float bias_row[8][OROWS];       // b0+b02+b12 + b01*s5(y) + b11*s11(y)

  const int t = threadIdx.x;
  // XCD-chunked swizzle (dispatch round-robins XCDs): remapped id r walks
  // (xstrip, yb, g, n) fastest-first; XCD k owns r in [512k, 512k+512).
  const int rmap = (blockIdx.x & 7) * 512 + (blockIdx.x >> 3);
  const int xstrip = rmap & 3, yb = (rmap >> 2) & 3;
  const int g = (rmap >> 4) & 15, n = rmap >> 8;
  const int xbase = xstrip * 32;
  const int c0 = g * 8;
  const int ch = t >> 5, xl = t & 31;
  const int c = c0 + ch;

  const int obase = yb * OROWS;
  const int oend  = obase + OROWS;
  const int sbase = (obase >= 5) ? (obase - 5) : 0;
  const int lastrow = (oend + 4 <= H_ - 1) ? (oend + 4) : (H_ - 1);
  const int nrows = lastrow - sbase + 1;     // 37 (edge) or 42 (middle)
  const int nchunk = (nrows + 15) >> 4;

  // per-thread weights in registers (41 floats)
  float w0t[9], w01t[5], w02t[5], w11t[11], w12t[11];
#pragma unroll
  for (int k = 0; k < 9; ++k)  w0t[k] = w0[c * 9 + k];
#pragma unroll
  for (int k = 0; k < 5; ++k)  { w01t[k] = w01[c * 5 + k]; w02t[k] = w02[c * 5 + k]; }
#pragma unroll
  for (int k = 0; k < 11; ++k) { w11t[k] = w11[c * 11 + k]; w12t[k] = w12[c * 11 + k]; }

  // boundary-bias table for this block's 32 outputs: one entry per thread
  {
    const int cb = t >> 5, oo = t & 31;
    const int y = obase + oo, cc = c0 + cb;
    float s5 = 0.f, s11 = 0.f;
#pragma unroll
    for (int k = 0; k < 5; ++k)  if ((unsigned)(y - 2 + k) < 128u) s5  += w02[cc * 5 + k];
#pragma unroll
    for (int k = 0; k < 11; ++k) if ((unsigned)(y - 5 + k) < 128u) s11 += w12[cc * 11 + k];
    bias_row[cb][oo] = b0[cc] + b02[cc] + b12[cc] + b01[cc] * s5 + b11[cc] * s11;
  }

  // staging decomposition: per-thread constants hoisted out of the chunk loop
  int s_rs[6];
  unsigned s_ok[6];
  const float* s_ptr[6];
  float* s_dst[6];
#pragma unroll
  for (int i = 0; i < 6; ++i) {
    int id = i * 256 + t;
    int chs = id / 192;
    int rem = id - chs * 192;
    int rs = rem / 12;
    int c4 = rem - rs * 12;
    int gx = xbase - 8 + c4 * 4;
    s_rs[i] = rs;
    s_ok[i] = ((unsigned)gx < 128u) ? 1u : 0u;
    s_ptr[i] = x + (size_t)(n * C_ + c0 + chs) * HW_ + gx;
    s_dst[i] = &xs[chs][rs][c4 * 4];
  }

  float4 pf[6];
  auto issue = [&](int cidx) {
    const int r0_ = sbase + cidx * 16;
#pragma unroll
    for (int i = 0; i < 6; ++i) {
      const int gy = r0_ + s_rs[i];
      float4 v = make_float4(0.f, 0.f, 0.f, 0.f);
      if (s_ok[i] && gy <= lastrow)
        v = *(const float4*)(s_ptr[i] + gy * W_);
      pf[i] = v;
    }
  };
  auto commit = [&]() {
#pragma unroll
    for (int i = 0; i < 6; ++i) *(float4*)s_dst[i] = pf[i];
  };

  float acc[16];
#pragma unroll
  for (int i = 0; i < 16; ++i) acc[i] = 0.f;

  unsigned short* wsp = ws + (size_t)(n * 16 + g) * HW_ * 8;

  issue(0);
  commit();
  __syncthreads();

  for (int cidx = 0; cidx < nchunk; ++cidx) {
    issue(cidx + 1);                         // prefetch next chunk into regs
    const int r0g = sbase + cidx * 16;       // global row of chunk start
    const int rem_rows = nrows - cidx * 16;
    const int rlim = rem_rows < 16 ? rem_rows : 16;
#pragma unroll
    for (int rr = 0; rr < 16; ++rr) {
      if (rr < rlim) {
        float win[11];
#pragma unroll
        for (int k = 0; k < 11; ++k) win[k] = xs[ch][rr][xl + 3 + k];
        // horizontal filters share the window
        float h11 = w11t[0] * win[0];
#pragma unroll
        for (int k = 1; k < 11; ++k) h11 += w11t[k] * win[k];
        float h5 = w01t[0] * win[3];
#pragma unroll
        for (int k = 1; k < 5; ++k) h5 += w01t[k] * win[3 + k];
        float r0v = w0t[0] * win[4] + w0t[1] * win[5] + w0t[2] * win[6];
        float r1v = w0t[3] * win[4] + w0t[4] * win[5] + w0t[5] * win[6];
        float r2v = w0t[6] * win[4] + w0t[7] * win[5] + w0t[8] * win[6];
        // vertical scatter into circular accumulators (compile-time slots;
        // chunk starts are ≡ 0 mod 16 in local rows, so rr-based slots hold)
#pragma unroll
        for (int tt = 0; tt < 11; ++tt) acc[(rr + 5 - tt) & 15] += w12t[tt] * h11;
#pragma unroll
        for (int tt = 0; tt < 5; ++tt)  acc[(rr + 2 - tt) & 15] += w02t[tt] * h5;
        acc[(rr + 1) & 15]  += r0v;
        acc[rr & 15]        += r1v;
        acc[(rr + 15) & 15] += r2v;
        // output o_e = r0g+rr-5 is complete (or is warmup garbage: zero it).
        const int o_e = r0g + rr - 5;
        const int slot = (rr + 11) & 15;
        if (o_e >= obase)
          ebuf[rr][ch][xl] = (unsigned short)f2bf(acc[slot] + bias_row[ch][o_e - obase]);
        acc[slot] = 0.f;
      }
    }
    __syncthreads();                         // ebuf complete; xs free
    // cooperative writeout: emitted o-rows, 16B per thread-pixel, contiguous
    for (int id = t; id < 512; id += 256) {
      int orr = id >> 5, x2 = id & 31;
      int o = r0g + orr - 5;
      if (orr < rlim && o >= obase) {
        unsigned u0 = ebuf[orr][0][x2] | ((unsigned)ebuf[orr][1][x2] << 16);
        unsigned u1 = ebuf[orr][2][x2] | ((unsigned)ebuf[orr][3][x2] << 16);
        unsigned u2 = ebuf[orr][4][x2] | ((unsigned)ebuf[orr][5][x2] << 16);
        unsigned u3 = ebuf[orr][6][x2] | ((unsigned)ebuf[orr][7][x2] << 16);
        uint4 pk; pk.x = u0; pk.y = u1; pk.z = u2; pk.w = u3;
        *(uint4*)(wsp + (size_t)(o * W_ + xbase + x2) * 8) = pk;
      }
    }
    if (cidx + 1 < nchunk) commit();         // regs->LDS for next chunk
    __syncthreads();
  }
  // drain outputs 123..127 (bottom y-block only; they complete at row 127)
  if (oend == H_) {
    __syncthreads();
#pragma unroll
    for (int orr = 0; orr < 5; ++orr) {
      const int o = H_ - 5 + orr;
      const int slot = (o - sbase) & 15;
      ebuf[orr][ch][xl] = (unsigned short)f2bf(acc[slot] + bias_row[ch][o - obase]);
    }
    __syncthreads();
    if (t < 160) {
      int orr = t >> 5, x2 = t & 31;
      int o = H_ - 5 + orr;
      unsigned u0 = ebuf[orr][0][x2] | ((unsigned)ebuf[orr][1][x2] << 16);
      unsigned u1 = ebuf[orr][2][x2] | ((unsigned)ebuf[orr][3][x2] << 16);
      unsigned u2 = ebuf[orr][4][x2] | ((unsigned)ebuf[orr][5][x2] << 16);
      unsigned u3 = ebuf[orr][6][x2] | ((unsigned)ebuf[orr][7][x2] << 16);
      uint4 pk; pk.x = u0; pk.y = u1; pk.z = u2; pk.w = u3;
      *(uint4*)(wsp + (size_t)(o * W_ + xbase + x2) * 8) = pk;
    }
  }
}

// ---------------------------------------------------------------------------
// Kernel 2: 1x1 channel mix via MFMA, A (=w3) resident in registers, no LDS.
// Wave w owns output channels [32w, 32w+32); block covers 64 pixels (4096
// blocks). Fully-unrolled pixel loop so the compiler can pipeline next-iter
// loads over MFMA + epilogue (no aliasing: all pointers __restrict__).
// ---------------------------------------------------------------------------
constexpr int PXB = 64;

__global__ __launch_bounds__(256, 4) void k_mix(
    const float* __restrict__ x,
    const float* __restrict__ w3, const float* __restrict__ b3,
    const unsigned short* __restrict__ ws,
    float* __restrict__ out)
{
  const int t = threadIdx.x;
  const int wv = t >> 6, lane = t & 63, q = lane >> 4, lp = lane & 15;
  const int n = blockIdx.y;
  const int px0 = blockIdx.x * PXB;

  // A fragments: rows o = 32*wv + 16*m + lp, k-slice ks*32 + q*8 (bf16-packed)
  s8v A[2][4];
  float b3v[2][4];
#pragma unroll
  for (int m = 0; m < 2; ++m) {
    const int o = 32 * wv + 16 * m + lp;
#pragma unroll
    for (int ks = 0; ks < 4; ++ks) {
      const float* src = w3 + o * 128 + ks * 32 + q * 8;
      float4 f0 = *(const float4*)src;
      float4 f1 = *(const float4*)(src + 4);
      union { s8v v; unsigned u[4]; } pk;
      pk.u[0] = f2bf(f0.x) | (f2bf(f0.y) << 16);
      pk.u[1] = f2bf(f0.z) | (f2bf(f0.w) << 16);
      pk.u[2] = f2bf(f1.x) | (f2bf(f1.y) << 16);
      pk.u[3] = f2bf(f1.z) | (f2bf(f1.w) << 16);
      A[m][ks] = pk.v;
    }
#pragma unroll
    for (int r = 0; r < 4; ++r) b3v[m][r] = b3[32 * wv + 16 * m + 4 * q + r];
  }

  const unsigned short* wsn = ws + (size_t)n * 16 * HW_ * 8;

#pragma unroll
  for (int npg = 0; npg < PXB / 16; ++npg) {
    const int pp = px0 + npg * 16 + lp;
    s8v B[4];
#pragma unroll
    for (int ks = 0; ks < 4; ++ks) {
      const int gg = ks * 4 + q;                 // channel-group for k = ks*32+q*8
      B[ks] = *(const s8v*)(wsn + ((size_t)gg * HW_ + pp) * 8);
    }
    // hoist the x (residual-multiply) loads so they overlap the MFMA chain
    float xv[2][4];
#pragma unroll
    for (int m = 0; m < 2; ++m)
#pragma unroll
      for (int r = 0; r < 4; ++r) {
        const int o = 32 * wv + 16 * m + 4 * q + r;
        xv[m][r] = x[((size_t)(n * C_ + o) << 14) + pp];
      }
    f4v acc[2] = {{0.f,0.f,0.f,0.f},{0.f,0.f,0.f,0.f}};
#pragma unroll
    for (int ks = 0; ks < 4; ++ks) {
#pragma unroll
      for (int m = 0; m < 2; ++m)
        acc[m] = __builtin_amdgcn_mfma_f32_16x16x32_bf16(A[m][ks], B[ks], acc[m], 0, 0, 0);
    }
#pragma unroll
    for (int m = 0; m < 2; ++m)
#pragma unroll
      for (int r = 0; r < 4; ++r) {
        const int o = 32 * wv + 16 * m + 4 * q + r;   // D row = q*4+r
        const size_t idx = ((size_t)(n * C_ + o) << 14) + pp;
        out[idx] = (acc[m][r] + b3v[m][r]) * xv[m][r];
      }
  }
}

extern "C" void kernel_launch(void* const* d_in, const int* in_sizes, int n_in,
                              void* d_out, int out_size, void* d_ws, size_t ws_size,
                              hipStream_t stream) {
  const float* x   = (const float*)d_in[0];
  const float* w0  = (const float*)d_in[1];
  const float* b0  = (const float*)d_in[2];
  const float* w01 = (const float*)d_in[3];
  const float* b01 = (const float*)d_in[4];
  const float* w02 = (const float*)d_in[5];
  const float* b02 = (const float*)d_in[6];
  const float* w11 = (const float*)d_in[7];
  const float* b11 = (const float*)d_in[8];
  const float* w12 = (const float*)d_in[9];
  const float* b12 = (const float*)d_in[10];
  const float* w3  = (const float*)d_in[11];
  const float* b3  = (const float*)d_in[12];
  unsigned short* ws = (unsigned short*)d_ws;   // 16*16*16384*8*2 = 64 MiB
  float* out = (float*)d_out;

  dim3 g1(4 * S_ * 16 * 16);   // 1-D grid, XCD-chunked swizzle inside
  k_dw<<<g1, 256, 0, stream>>>(x, w0, b0, w01, b01, w02, b02, w11, b11, w12, b12, ws);

  dim3 g2(HW_ / PXB, 16);      // (64-px blocks, batch)
  k_mix<<<g2, 256, 0, stream>>>(x, w3, b3, ws, out);
}

// Round 3
// 547.250 us; speedup vs baseline: 1.1497x; 1.1497x over previous
//
#include <hip/hip_runtime.h>
#include <stdint.h>

using f4v = __attribute__((ext_vector_type(4))) float;
using s8v = __attribute__((ext_vector_type(8))) short;

constexpr int C_ = 128, H_ = 128, W_ = 128, HW_ = H_ * W_;
constexpr int S_ = 4;             // y-splits for k_dw
constexpr int OROWS = H_ / S_;    // 32 output rows per block
static_assert(OROWS == 32, "bias table indexing assumes 32 rows/block");

__device__ __forceinline__ unsigned f2bf(float f) {
  union { float f; unsigned u; } v; v.f = f;
  return (v.u + 0x7FFFu + ((v.u >> 16) & 1u)) >> 16;   // RTNE
}

// ---------------------------------------------------------------------------
// Kernel 1: fused depthwise branches -> add (bf16), column-sweep with circular
// register accumulators. Block = 8 channels x 32-col strip x 32 output rows.
// Round-3: back to round-1 structure (no XCD swizzle, no async-stage regs).
// KEY FIX: amdgpu_waves_per_eu(4,4) pins the occupancy target. launch_bounds
// (256,4) alone let the backend chase 8 waves/EU -> 64 VGPRs -> spilled the
// 41 weight floats to scratch (WRITE_SIZE 64->272 MiB smoking gun). Pinning
// min=max=4 gives a 128-VGPR budget the ~85-reg live set fits without spill;
// LDS (33.8 KB) caps at 4 blocks/CU anyway, so 8 waves/EU was unreachable.
// ws layout: [n][g=c/8][p=h*128+w][c%8] bf16 (16B per pixel-group).
// ---------------------------------------------------------------------------
__global__ __launch_bounds__(256)
__attribute__((amdgpu_waves_per_eu(4, 4)))
void k_dw(
    const float* __restrict__ x,
    const float* __restrict__ w0,  const float* __restrict__ b0,
    const float* __restrict__ w01, const float* __restrict__ b01,
    const float* __restrict__ w02, const float* __restrict__ b02,
    const float* __restrict__ w11, const float* __restrict__ b11,
    const float* __restrict__ w12, const float* __restrict__ b12,
    unsigned short* __restrict__ ws)
{
  __shared__ float xs[8][16][48];            // 16-row chunk + 8-col halo each side
  __shared__ unsigned short ebuf[16][8][32]; // emit transpose buffer [row][ch][x]
  __shared__ float bias_row[8][OROWS];       // b0+b02+b12 + b01*s5(y) + b11*s11(y)

  const int t = threadIdx.x;
  const int xstrip = blockIdx.x & 3, yb = blockIdx.x >> 2;
  const int g = blockIdx.y, n = blockIdx.z;
  const int xbase = xstrip * 32;
  const int c0 = g * 8;
  const int ch = t >> 5, xl = t & 31;
  const int c = c0 + ch;

  const int obase = yb * OROWS;
  const int oend  = obase + OROWS;
  const int sbase = (obase >= 5) ? (obase - 5) : 0;
  const int lastrow = (oend + 4 <= H_ - 1) ? (oend + 4) : (H_ - 1);
  const int nrows = lastrow - sbase + 1;     // 37 (edge) or 42 (middle)
  const int nchunk = (nrows + 15) >> 4;

  // per-thread weights in registers (41 floats)
  float w0t[9], w01t[5], w02t[5], w11t[11], w12t[11];
#pragma unroll
  for (int k = 0; k < 9; ++k)  w0t[k] = w0[c * 9 + k];
#pragma unroll
  for (int k = 0; k < 5; ++k)  { w01t[k] = w01[c * 5 + k]; w02t[k] = w02[c * 5 + k]; }
#pragma unroll
  for (int k = 0; k < 11; ++k) { w11t[k] = w11[c * 11 + k]; w12t[k] = w12[c * 11 + k]; }

  // boundary-bias table for this block's 32 outputs: one entry per thread
  {
    const int cb = t >> 5, oo = t & 31;
    const int y = obase + oo, cc = c0 + cb;
    float s5 = 0.f, s11 = 0.f;
#pragma unroll
    for (int k = 0; k < 5; ++k)  if ((unsigned)(y - 2 + k) < 128u) s5  += w02[cc * 5 + k];
#pragma unroll
    for (int k = 0; k < 11; ++k) if ((unsigned)(y - 5 + k) < 128u) s11 += w12[cc * 11 + k];
    bias_row[cb][oo] = b0[cc] + b02[cc] + b12[cc] + b01[cc] * s5 + b11[cc] * s11;
  }

  float acc[16];
#pragma unroll
  for (int i = 0; i < 16; ++i) acc[i] = 0.f;

  unsigned short* wsp = ws + (size_t)(n * 16 + g) * HW_ * 8;

  for (int cidx = 0; cidx < nchunk; ++cidx) {
    const int r0g = sbase + cidx * 16;       // global row of chunk start
    const int rem_rows = nrows - cidx * 16;
    const int rlim = rem_rows < 16 ? rem_rows : 16;
    __syncthreads();
    // stage up to 16 rows x 48 cols x 8 ch (OOB / beyond-rlim -> 0), float4
#pragma unroll
    for (int i = 0; i < 6; ++i) {
      int id = i * 256 + t;
      int chs = id / 192;
      int rem = id - chs * 192;
      int rs = rem / 12;
      int c4 = rem - rs * 12;
      int gx = xbase - 8 + c4 * 4;
      float4 v = make_float4(0.f, 0.f, 0.f, 0.f);
      if ((unsigned)gx < 128u && rs < rlim)
        v = *(const float4*)(x + (size_t)((n * C_ + c0 + chs) * H_ + r0g + rs) * W_ + gx);
      *(float4*)&xs[chs][rs][c4 * 4] = v;
    }
    __syncthreads();
#pragma unroll
    for (int rr = 0; rr < 16; ++rr) {
      if (rr < rlim) {
        float win[11];
#pragma unroll
        for (int k = 0; k < 11; ++k) win[k] = xs[ch][rr][xl + 3 + k];
        // horizontal filters share the window
        float h11 = w11t[0] * win[0];
#pragma unroll
        for (int k = 1; k < 11; ++k) h11 += w11t[k] * win[k];
        float h5 = w01t[0] * win[3];
#pragma unroll
        for (int k = 1; k < 5; ++k) h5 += w01t[k] * win[3 + k];
        float r0v = w0t[0] * win[4] + w0t[1] * win[5] + w0t[2] * win[6];
        float r1v = w0t[3] * win[4] + w0t[4] * win[5] + w0t[5] * win[6];
        float r2v = w0t[6] * win[4] + w0t[7] * win[5] + w0t[8] * win[6];
        // vertical scatter into circular accumulators (compile-time slots;
        // chunk starts are ≡ 0 mod 16 in local rows, so rr-based slots hold)
#pragma unroll
        for (int tt = 0; tt < 11; ++tt) acc[(rr + 5 - tt) & 15] += w12t[tt] * h11;
#pragma unroll
        for (int tt = 0; tt < 5; ++tt)  acc[(rr + 2 - tt) & 15] += w02t[tt] * h5;
        acc[(rr + 1) & 15]  += r0v;
        acc[rr & 15]        += r1v;
        acc[(rr + 15) & 15] += r2v;
        // output o_e = r0g+rr-5 is complete (or is warmup garbage: zero it).
        // o_e < oend is guaranteed for rr < rlim since lastrow <= oend+4.
        const int o_e = r0g + rr - 5;
        const int slot = (rr + 11) & 15;
        if (o_e >= obase)
          ebuf[rr][ch][xl] = (unsigned short)f2bf(acc[slot] + bias_row[ch][o_e - obase]);
        acc[slot] = 0.f;
      }
    }
    __syncthreads();
    // cooperative writeout: emitted o-rows, 16B per thread-pixel, contiguous
    for (int id = t; id < 512; id += 256) {
      int orr = id >> 5, x2 = id & 31;
      int o = r0g + orr - 5;
      if (orr < rlim && o >= obase) {
        unsigned u0 = ebuf[orr][0][x2] | ((unsigned)ebuf[orr][1][x2] << 16);
        unsigned u1 = ebuf[orr][2][x2] | ((unsigned)ebuf[orr][3][x2] << 16);
        unsigned u2 = ebuf[orr][4][x2] | ((unsigned)ebuf[orr][5][x2] << 16);
        unsigned u3 = ebuf[orr][6][x2] | ((unsigned)ebuf[orr][7][x2] << 16);
        uint4 pk; pk.x = u0; pk.y = u1; pk.z = u2; pk.w = u3;
        *(uint4*)(wsp + (size_t)(o * W_ + xbase + x2) * 8) = pk;
      }
    }
  }
  // drain outputs 123..127 (bottom y-block only; they complete at row 127)
  if (oend == H_) {
    __syncthreads();
#pragma unroll
    for (int orr = 0; orr < 5; ++orr) {
      const int o = H_ - 5 + orr;
      const int slot = (o - sbase) & 15;
      ebuf[orr][ch][xl] = (unsigned short)f2bf(acc[slot] + bias_row[ch][o - obase]);
    }
    __syncthreads();
    if (t < 160) {
      int orr = t >> 5, x2 = t & 31;
      int o = H_ - 5 + orr;
      unsigned u0 = ebuf[orr][0][x2] | ((unsigned)ebuf[orr][1][x2] << 16);
      unsigned u1 = ebuf[orr][2][x2] | ((unsigned)ebuf[orr][3][x2] << 16);
      unsigned u2 = ebuf[orr][4][x2] | ((unsigned)ebuf[orr][5][x2] << 16);
      unsigned u3 = ebuf[orr][6][x2] | ((unsigned)ebuf[orr][7][x2] << 16);
      uint4 pk; pk.x = u0; pk.y = u1; pk.z = u2; pk.w = u3;
      *(uint4*)(wsp + (size_t)(o * W_ + xbase + x2) * 8) = pk;
    }
  }
}

// ---------------------------------------------------------------------------
// Kernel 2: 1x1 channel mix via MFMA, A (=w3) resident in registers, no LDS.
// Wave w owns output channels [32w, 32w+32); block covers 64 pixels (4096
// blocks). Same waves_per_eu pinning as insurance against spill-for-occupancy
// (live set ~85 regs: A=32, B=16, acc=8, xv=8, b3v=8 + addressing).
// ---------------------------------------------------------------------------
constexpr int PXB = 64;

__global__ __launch_bounds__(256)
__attribute__((amdgpu_waves_per_eu(4, 4)))
void k_mix(
    const float* __restrict__ x,
    const float* __restrict__ w3, const float* __restrict__ b3,
    const unsigned short* __restrict__ ws,
    float* __restrict__ out)
{
  const int t = threadIdx.x;
  const int wv = t >> 6, lane = t & 63, q = lane >> 4, lp = lane & 15;
  const int n = blockIdx.y;
  const int px0 = blockIdx.x * PXB;

  // A fragments: rows o = 32*wv + 16*m + lp, k-slice ks*32 + q*8 (bf16-packed)
  s8v A[2][4];
  float b3v[2][4];
#pragma unroll
  for (int m = 0; m < 2; ++m) {
    const int o = 32 * wv + 16 * m + lp;
#pragma unroll
    for (int ks = 0; ks < 4; ++ks) {
      const float* src = w3 + o * 128 + ks * 32 + q * 8;
      float4 f0 = *(const float4*)src;
      float4 f1 = *(const float4*)(src + 4);
      union { s8v v; unsigned u[4]; } pk;
      pk.u[0] = f2bf(f0.x) | (f2bf(f0.y) << 16);
      pk.u[1] = f2bf(f0.z) | (f2bf(f0.w) << 16);
      pk.u[2] = f2bf(f1.x) | (f2bf(f1.y) << 16);
      pk.u[3] = f2bf(f1.z) | (f2bf(f1.w) << 16);
      A[m][ks] = pk.v;
    }
#pragma unroll
    for (int r = 0; r < 4; ++r) b3v[m][r] = b3[32 * wv + 16 * m + 4 * q + r];
  }

  const unsigned short* wsn = ws + (size_t)n * 16 * HW_ * 8;

#pragma unroll
  for (int npg = 0; npg < PXB / 16; ++npg) {
    const int pp = px0 + npg * 16 + lp;
    s8v B[4];
#pragma unroll
    for (int ks = 0; ks < 4; ++ks) {
      const int gg = ks * 4 + q;                 // channel-group for k = ks*32+q*8
      B[ks] = *(const s8v*)(wsn + ((size_t)gg * HW_ + pp) * 8);
    }
    // hoist the x (residual-multiply) loads so they overlap the MFMA chain
    float xv[2][4];
#pragma unroll
    for (int m = 0; m < 2; ++m)
#pragma unroll
      for (int r = 0; r < 4; ++r) {
        const int o = 32 * wv + 16 * m + 4 * q + r;
        xv[m][r] = x[((size_t)(n * C_ + o) << 14) + pp];
      }
    f4v acc[2] = {{0.f,0.f,0.f,0.f},{0.f,0.f,0.f,0.f}};
#pragma unroll
    for (int ks = 0; ks < 4; ++ks) {
#pragma unroll
      for (int m = 0; m < 2; ++m)
        acc[m] = __builtin_amdgcn_mfma_f32_16x16x32_bf16(A[m][ks], B[ks], acc[m], 0, 0, 0);
    }
#pragma unroll
    for (int m = 0; m < 2; ++m)
#pragma unroll
      for (int r = 0; r < 4; ++r) {
        const int o = 32 * wv + 16 * m + 4 * q + r;   // D row = q*4+r
        const size_t idx = ((size_t)(n * C_ + o) << 14) + pp;
        out[idx] = (acc[m][r] + b3v[m][r]) * xv[m][r];
      }
  }
}

extern "C" void kernel_launch(void* const* d_in, const int* in_sizes, int n_in,
                              void* d_out, int out_size, void* d_ws, size_t ws_size,
                              hipStream_t stream) {
  const float* x   = (const float*)d_in[0];
  const float* w0  = (const float*)d_in[1];
  const float* b0  = (const float*)d_in[2];
  const float* w01 = (const float*)d_in[3];
  const float* b01 = (const float*)d_in[4];
  const float* w02 = (const float*)d_in[5];
  const float* b02 = (const float*)d_in[6];
  const float* w11 = (const float*)d_in[7];
  const float* b11 = (const float*)d_in[8];
  const float* w12 = (const float*)d_in[9];
  const float* b12 = (const float*)d_in[10];
  const float* w3  = (const float*)d_in[11];
  const float* b3  = (const float*)d_in[12];
  unsigned short* ws = (unsigned short*)d_ws;   // 16*16*16384*8*2 = 64 MiB
  float* out = (float*)d_out;

  dim3 g1(4 * S_, 16, 16);   // (x-strips * y-splits, channel groups, batch)
  k_dw<<<g1, 256, 0, stream>>>(x, w0, b0, w01, b01, w02, b02, w11, b11, w12, b12, ws);

  dim3 g2(HW_ / PXB, 16);    // (64-px blocks, batch)
  k_mix<<<g2, 256, 0, stream>>>(x, w3, b3, ws, out);
}

// Round 5
// 362.348 us; speedup vs baseline: 1.7364x; 1.5103x over previous
//
#include <hip/hip_runtime.h>
#include <stdint.h>

using f4v = __attribute__((ext_vector_type(4))) float;
using s8v = __attribute__((ext_vector_type(8))) short;

constexpr int C_ = 128, H_ = 128, W_ = 128, HW_ = H_ * W_;
constexpr int S_ = 4;             // y-splits for k_dw
constexpr int OROWS = H_ / S_;    // 32 output rows per block
constexpr int CHB = 4;            // channels per k_dw block (1 per wave-pair; wave-uniform)
constexpr int TPB = 512;
static_assert(OROWS == 32, "bias table indexing assumes 32 rows/block");

__device__ __forceinline__ unsigned f2bf(float f) {
  union { float f; unsigned u; } v; v.f = f;
  return (v.u + 0x7FFFu + ((v.u >> 16) & 1u)) >> 16;   // RTNE
}

// force a wave-uniform float into an SGPR
__device__ __forceinline__ float sgpr(float v) {
  return __int_as_float(__builtin_amdgcn_readfirstlane(__float_as_int(v)));
}

// ---------------------------------------------------------------------------
// Kernel 1: fused depthwise branches -> add (bf16).
// Round-5: round-4 structure with the drain-writeout bug fixed (was
// `if (t < 640)` with only 512 threads -> output row 127 never written).
//  * Block = 512 thr = 4 channels x 128 px (FULL row width). ch = t>>7 is
//    wave-uniform -> all 41 filter taps live in SGPRs (readfirstlane), so the
//    VGPR live set (~50) fits the 64-VGPR allocation the backend insists on.
//    No spills (rounds 1-3: 208 MiB/dispatch scratch writes at VGPR=64).
//  * Full-width rows: staging loads are aligned 512-B spans, no x-halo ->
//    kills the 2-3x FETCH line-split amplification. Halo is LDS zero-pad
//    columns (8 left, 8 right) written once.
//  * ws layout [n][g=c/4][px][c%4] bf16, 8-B px-granules (dense,
//    single-writer lines). k_mix reads two uint2 per B fragment.
// Accumulator/slot/boundary logic transplanted unchanged from the verified
// round-1/3 kernel (chunk starts ≡ 0 mod 16 -> compile-time slots).
// ---------------------------------------------------------------------------
__global__ __launch_bounds__(TPB) void k_dw(
    const float* __restrict__ x,
    const float* __restrict__ w0,  const float* __restrict__ b0,
    const float* __restrict__ w01, const float* __restrict__ b01,
    const float* __restrict__ w02, const float* __restrict__ b02,
    const float* __restrict__ w11, const float* __restrict__ b11,
    const float* __restrict__ w12, const float* __restrict__ b12,
    unsigned short* __restrict__ ws)
{
  __shared__ float xs[CHB][16][144];          // 128 px at cols 8..135; pads 0..7,136..143 = 0
  __shared__ unsigned short ebuf[16][CHB][128];
  __shared__ float bias_row[CHB][OROWS];

  const int t = threadIdx.x;
  const int yb = blockIdx.x, g = blockIdx.y, n = blockIdx.z;
  const int ch = t >> 7, xl = t & 127;        // ch uniform per wave
  const int c0 = g * CHB, c = c0 + ch;

  const int obase = yb * OROWS;
  const int oend  = obase + OROWS;
  const int sbase = (obase >= 5) ? (obase - 5) : 0;
  const int lastrow = (oend + 4 <= H_ - 1) ? (oend + 4) : (H_ - 1);
  const int nrows = lastrow - sbase + 1;      // 37 (edge) or 42 (middle)
  const int nchunk = (nrows + 15) >> 4;

  // wave-uniform weights -> SGPRs (41 scalars)
  float w0t[9], w01t[5], w02t[5], w11t[11], w12t[11];
#pragma unroll
  for (int k = 0; k < 9; ++k)  w0t[k] = sgpr(w0[c * 9 + k]);
#pragma unroll
  for (int k = 0; k < 5; ++k)  { w01t[k] = sgpr(w01[c * 5 + k]); w02t[k] = sgpr(w02[c * 5 + k]); }
#pragma unroll
  for (int k = 0; k < 11; ++k) { w11t[k] = sgpr(w11[c * 11 + k]); w12t[k] = sgpr(w12[c * 11 + k]); }

  // boundary-bias table: 4 ch x 32 outputs
  if (t < CHB * OROWS) {
    const int cb = t >> 5, oo = t & 31;
    const int y = obase + oo, cc = c0 + cb;
    float s5 = 0.f, s11 = 0.f;
#pragma unroll
    for (int k = 0; k < 5; ++k)  if ((unsigned)(y - 2 + k) < 128u) s5  += w02[cc * 5 + k];
#pragma unroll
    for (int k = 0; k < 11; ++k) if ((unsigned)(y - 5 + k) < 128u) s11 += w12[cc * 11 + k];
    bias_row[cb][oo] = b0[cc] + b02[cc] + b12[cc] + b01[cc] * s5 + b11[cc] * s11;
  }

  // zero the halo pad columns once (cols 0..7 and 136..143 of every row)
  if (t < 256) {
    const int zc = t >> 6, zr = (t >> 2) & 15, zq = t & 3;
    const int col = (zq < 2) ? zq * 4 : 136 + (zq - 2) * 4;
    *(float4*)&xs[zc][zr][col] = make_float4(0.f, 0.f, 0.f, 0.f);
  }

  float acc[16];
#pragma unroll
  for (int i = 0; i < 16; ++i) acc[i] = 0.f;

  unsigned short* wsp = ws + (size_t)(n * 32 + g) * HW_ * 4;

  for (int cidx = 0; cidx < nchunk; ++cidx) {
    const int r0g = sbase + cidx * 16;        // global row of chunk start
    const int rem_rows = nrows - cidx * 16;
    const int rlim = rem_rows < 16 ? rem_rows : 16;
    __syncthreads();
    // stage 4 ch x up to 16 rows x 128 px (beyond-rlim -> 0); aligned float4
#pragma unroll
    for (int i = 0; i < 4; ++i) {
      const int id = i * TPB + t;             // 0..2047
      const int chs = id >> 9;
      const int rs  = (id >> 5) & 15;
      const int c4  = id & 31;
      float4 v = make_float4(0.f, 0.f, 0.f, 0.f);
      if (rs < rlim)
        v = *(const float4*)(x + (size_t)((n * C_ + c0 + chs) * H_ + r0g + rs) * W_ + c4 * 4);
      *(float4*)&xs[chs][rs][8 + c4 * 4] = v;
    }
    __syncthreads();
#pragma unroll
    for (int rr = 0; rr < 16; ++rr) {
      if (rr < rlim) {
        float win[11];                        // tap k reads px xl-5+k -> col xl+3+k
#pragma unroll
        for (int k = 0; k < 11; ++k) win[k] = xs[ch][rr][xl + 3 + k];
        float h11 = w11t[0] * win[0];
#pragma unroll
        for (int k = 1; k < 11; ++k) h11 += w11t[k] * win[k];
        float h5 = w01t[0] * win[3];
#pragma unroll
        for (int k = 1; k < 5; ++k) h5 += w01t[k] * win[3 + k];
        float r0v = w0t[0] * win[4] + w0t[1] * win[5] + w0t[2] * win[6];
        float r1v = w0t[3] * win[4] + w0t[4] * win[5] + w0t[5] * win[6];
        float r2v = w0t[6] * win[4] + w0t[7] * win[5] + w0t[8] * win[6];
        // vertical scatter into circular accumulators (compile-time slots)
#pragma unroll
        for (int tt = 0; tt < 11; ++tt) acc[(rr + 5 - tt) & 15] += w12t[tt] * h11;
#pragma unroll
        for (int tt = 0; tt < 5; ++tt)  acc[(rr + 2 - tt) & 15] += w02t[tt] * h5;
        acc[(rr + 1) & 15]  += r0v;
        acc[rr & 15]        += r1v;
        acc[(rr + 15) & 15] += r2v;
        // output o_e = r0g+rr-5 complete (or warmup garbage: reset only)
        const int o_e = r0g + rr - 5;
        const int slot = (rr + 11) & 15;
        if (o_e >= obase)
          ebuf[rr][ch][xl] = (unsigned short)f2bf(acc[slot] + bias_row[ch][o_e - obase]);
        acc[slot] = 0.f;
      }
    }
    __syncthreads();
    // writeout: pack 4 ch shorts -> 8-B granule, dense contiguous rows
    for (int id = t; id < 2048; id += TPB) {
      const int orr = id >> 7, px = id & 127;
      const int o = r0g + orr - 5;
      if (orr < rlim && o >= obase) {
        uint2 pk;
        pk.x = ebuf[orr][0][px] | ((unsigned)ebuf[orr][1][px] << 16);
        pk.y = ebuf[orr][2][px] | ((unsigned)ebuf[orr][3][px] << 16);
        *(uint2*)(wsp + ((size_t)o * W_ + px) * 4) = pk;
      }
    }
  }
  // drain outputs 123..127 (bottom y-block only)
  if (oend == H_) {
    __syncthreads();
#pragma unroll
    for (int orr = 0; orr < 5; ++orr) {
      const int o = H_ - 5 + orr;
      const int slot = (o - sbase) & 15;
      ebuf[orr][ch][xl] = (unsigned short)f2bf(acc[slot] + bias_row[ch][o - obase]);
    }
    __syncthreads();
    // FIX: 640 (5 rows x 128 px) work items > 512 threads -> strided loop.
    // Round-4's `if (t < 640)` left output row 127 unwritten (absmax 15.5).
    for (int id = t; id < 640; id += TPB) {
      const int orr = id >> 7, px = id & 127;
      const int o = H_ - 5 + orr;
      uint2 pk;
      pk.x = ebuf[orr][0][px] | ((unsigned)ebuf[orr][1][px] << 16);
      pk.y = ebuf[orr][2][px] | ((unsigned)ebuf[orr][3][px] << 16);
      *(uint2*)(wsp + ((size_t)o * W_ + px) * 4) = pk;
    }
  }
}

// ---------------------------------------------------------------------------
// Kernel 2: 1x1 channel mix via MFMA, A (=w3) resident in registers, no LDS.
// Wave w owns output channels [32w, 32w+32); block covers 64 pixels (4096
// blocks). Plain launch_bounds (no occupancy attribute -> no spill trap).
// B fragments come from 4-ch granules: two uint2 loads, same k-order.
// ---------------------------------------------------------------------------
constexpr int PXB = 64;

__global__ __launch_bounds__(256) void k_mix(
    const float* __restrict__ x,
    const float* __restrict__ w3, const float* __restrict__ b3,
    const unsigned short* __restrict__ ws,
    float* __restrict__ out)
{
  const int t = threadIdx.x;
  const int wv = t >> 6, lane = t & 63, q = lane >> 4, lp = lane & 15;
  const int n = blockIdx.y;
  const int px0 = blockIdx.x * PXB;

  // A fragments: rows o = 32*wv + 16*m + lp, k-slice ks*32 + q*8 (bf16-packed)
  s8v A[2][4];
  float b3v[2][4];
#pragma unroll
  for (int m = 0; m < 2; ++m) {
    const int o = 32 * wv + 16 * m + lp;
#pragma unroll
    for (int ks = 0; ks < 4; ++ks) {
      const float* src = w3 + o * 128 + ks * 32 + q * 8;
      float4 f0 = *(const float4*)src;
      float4 f1 = *(const float4*)(src + 4);
      union { s8v v; unsigned u[4]; } pk;
      pk.u[0] = f2bf(f0.x) | (f2bf(f0.y) << 16);
      pk.u[1] = f2bf(f0.z) | (f2bf(f0.w) << 16);
      pk.u[2] = f2bf(f1.x) | (f2bf(f1.y) << 16);
      pk.u[3] = f2bf(f1.z) | (f2bf(f1.w) << 16);
      A[m][ks] = pk.v;
    }
#pragma unroll
    for (int r = 0; r < 4; ++r) b3v[m][r] = b3[32 * wv + 16 * m + 4 * q + r];
  }

  const unsigned short* wsn = ws + (size_t)n * 32 * HW_ * 4;

#pragma unroll
  for (int npg = 0; npg < PXB / 16; ++npg) {
    const int pp = px0 + npg * 16 + lp;
    s8v B[4];
#pragma unroll
    for (int ks = 0; ks < 4; ++ks) {
      const int gg8 = ks * 4 + q;            // 8-ch group for k = ks*32+q*8
      const unsigned short* gsrc = wsn + ((size_t)(gg8 * 2) * HW_ + pp) * 4;
      union { s8v v; uint2 u2[2]; } pk;
      pk.u2[0] = *(const uint2*)gsrc;                    // ch 8*gg8+0..3
      pk.u2[1] = *(const uint2*)(gsrc + (size_t)HW_ * 4);// ch 8*gg8+4..7
      B[ks] = pk.v;
    }
    // hoist the x (residual-multiply) loads so they overlap the MFMA chain
    float xv[2][4];
#pragma unroll
    for (int m = 0; m < 2; ++m)
#pragma unroll
      for (int r = 0; r < 4; ++r) {
        const int o = 32 * wv + 16 * m + 4 * q + r;
        xv[m][r] = x[((size_t)(n * C_ + o) << 14) + pp];
      }
    f4v acc[2] = {{0.f,0.f,0.f,0.f},{0.f,0.f,0.f,0.f}};
#pragma unroll
    for (int ks = 0; ks < 4; ++ks) {
#pragma unroll
      for (int m = 0; m < 2; ++m)
        acc[m] = __builtin_amdgcn_mfma_f32_16x16x32_bf16(A[m][ks], B[ks], acc[m], 0, 0, 0);
    }
#pragma unroll
    for (int m = 0; m < 2; ++m)
#pragma unroll
      for (int r = 0; r < 4; ++r) {
        const int o = 32 * wv + 16 * m + 4 * q + r;   // D row = q*4+r
        const size_t idx = ((size_t)(n * C_ + o) << 14) + pp;
        out[idx] = (acc[m][r] + b3v[m][r]) * xv[m][r];
      }
  }
}

extern "C" void kernel_launch(void* const* d_in, const int* in_sizes, int n_in,
                              void* d_out, int out_size, void* d_ws, size_t ws_size,
                              hipStream_t stream) {
  const float* x   = (const float*)d_in[0];
  const float* w0  = (const float*)d_in[1];
  const float* b0  = (const float*)d_in[2];
  const float* w01 = (const float*)d_in[3];
  const float* b01 = (const float*)d_in[4];
  const float* w02 = (const float*)d_in[5];
  const float* b02 = (const float*)d_in[6];
  const float* w11 = (const float*)d_in[7];
  const float* b11 = (const float*)d_in[8];
  const float* w12 = (const float*)d_in[9];
  const float* b12 = (const float*)d_in[10];
  const float* w3  = (const float*)d_in[11];
  const float* b3  = (const float*)d_in[12];
  unsigned short* ws = (unsigned short*)d_ws;   // 16*32*16384*4*2 = 64 MiB
  float* out = (float*)d_out;

  dim3 g1(S_, 32, 16);       // (y-splits, 4-ch groups, batch)
  k_dw<<<g1, TPB, 0, stream>>>(x, w0, b0, w01, b01, w02, b02, w11, b11, w12, b12, ws);

  dim3 g2(HW_ / PXB, 16);    // (64-px blocks, batch)
  k_mix<<<g2, 256, 0, stream>>>(x, w3, b3, ws, out);
}